// Round 1
// 191.115 us; speedup vs baseline: 1.0105x; 1.0105x over previous
//
#include <hip/hip_runtime.h>
#include <math.h>

// Problem constants
constexpr int Bn   = 32;
constexpr int L    = 65536;            // T*K
constexpr int NCH  = 6;
constexpr int SPAN = 256;              // hexads (l-steps) per wave-span
constexpr int NS   = L / SPAN;         // 256 spans per batch row
constexpr int NIT  = SPAN / 64;        // 4 blocks of 64 per span
constexpr int ROW  = L * NCH;          // floats per row (imu/mn/out)
constexpr int EPW_ROW = (L - 1) * NCH; // floats per row (eps_walk)
constexpr int NWAVE = Bn * NS;         // 8192 wave-spans
constexpr float AF = 0.99999f;         // a = 1 - theta*dt (fp32, matches ref)
constexpr float DS_ACC  = 0.2f   * 0.004472135954999579f; // std*sqrt(2*theta*dt)
constexpr float DS_GYRO = 0.015f * 0.004472135954999579f;

// a^(lane+1) and a^(63-lane), double-accurate, computed once per thread
__device__ __forceinline__ void lane_pows(int lane, float& ap1, float& arev) {
    const double a = (double)AF;
    double t = a, p1 = 1.0, pr = 1.0;
    int e1 = lane + 1, er = 63 - lane;
    #pragma unroll
    for (int k = 0; k < 7; ++k) {
        if (e1 & (1 << k)) p1 *= t;
        if (er & (1 << k)) pr *= t;
        t *= t;
    }
    ap1 = (float)p1; arev = (float)pr;
}

__device__ __forceinline__ float a_pow64() {
    double t = (double)AF;
    #pragma unroll
    for (int k = 0; k < 6; ++k) t *= t;   // a^64
    return (float)t;
}

// load one hexad of scaled innovation x[6] for step l (handles l==0 seed)
__device__ __forceinline__ void load_x(const float* __restrict__ epw,
                                       const float* __restrict__ eps0,
                                       int b, int l, float x[6]) {
    int lm1 = (l == 0) ? 0 : l - 1;                 // clamp (safe addr)
    const float2* p = (const float2*)(epw + (size_t)b * EPW_ROW + (size_t)lm1 * NCH);
    float2 v0 = p[0], v1 = p[1], v2 = p[2];
    x[0] = v0.x * DS_ACC;  x[1] = v0.y * DS_ACC;  x[2] = v1.x * DS_ACC;
    x[3] = v1.y * DS_GYRO; x[4] = v2.x * DS_GYRO; x[5] = v2.y * DS_GYRO;
    if (l == 0) {                                   // bias0 seed = eps0*std0
        const float* e0 = eps0 + b * NCH;
        x[0] = e0[0] * 0.2f;   x[1] = e0[1] * 0.2f;   x[2] = e0[2] * 0.2f;
        x[3] = e0[3] * 0.015f; x[4] = e0[4] * 0.015f; x[5] = e0[5] * 0.015f;
    }
}

// ---------- K1: per-span weighted aggregates ----------
// P_s = sum_{i<SPAN} a^(SPAN-1-i) x[i]
//     = sum_t a^(63-t) * [ Horner over it with A64 of x(it,t) ]
// => per-lane Horner (loads all hoisted, no serialization), ONE weighted
//    butterfly per span instead of one per 64-block (4x fewer shuffles).
__global__ __launch_bounds__(256) void k_partials(
    const float* __restrict__ eps0,
    const float* __restrict__ epw,
    float* __restrict__ part)
{
    int lane = threadIdx.x & 63;
    int w = blockIdx.x * 4 + (threadIdx.x >> 6);   // wave-span id
    int b = w / NS, s = w % NS;

    float ap1, arev; lane_pows(lane, ap1, arev);
    const float A64 = a_pow64();
    int l0 = s * SPAN;

    // hoist ALL loads (independent addresses -> one vmcnt wait)
    float x[NIT][6];
    #pragma unroll
    for (int it = 0; it < NIT; ++it)
        load_x(epw, eps0, b, l0 + it * 64 + lane, x[it]);

    float v[6];
    #pragma unroll
    for (int c = 0; c < 6; ++c) {
        float h = x[0][c];
        #pragma unroll
        for (int it = 1; it < NIT; ++it) h = fmaf(A64, h, x[it][c]);
        v[c] = arev * h;
    }

    #pragma unroll
    for (int c = 0; c < 6; ++c) {
        #pragma unroll
        for (int m = 1; m < 64; m <<= 1) v[c] += __shfl_xor(v[c], m, 64);
    }

    if (lane < 6) {
        float r = v[0];
        if (lane == 1) r = v[1]; else if (lane == 2) r = v[2];
        else if (lane == 3) r = v[3]; else if (lane == 4) r = v[4];
        else if (lane == 5) r = v[5];
        part[(size_t)w * NCH + lane] = r;
    }
}

// ---------- K2: scan span aggregates per chain (tiny, double) ----------
__global__ __launch_bounds__(64) void k_scan(
    const float* __restrict__ part,
    float* __restrict__ carry)
{
    int lane = threadIdx.x;
    int chain = blockIdx.x;              // b*6 + c
    int b = chain / NCH, c = chain % NCH;

    double a = (double)AF;
    double A = a;
    #pragma unroll
    for (int k = 0; k < 8; ++k) A *= A;  // a^256 = a^SPAN
    double A4 = A * A; A4 *= A4;         // A^4 (per-lane span of 4 segments)

    int s0 = lane * 4;
    size_t base = (size_t)b * NS * NCH + c;
    float pv[4];
    #pragma unroll
    for (int k = 0; k < 4; ++k) pv[k] = part[base + (size_t)(s0 + k) * NCH];

    double t = 0.0;
    #pragma unroll
    for (int k = 0; k < 4; ++k) t = A * t + (double)pv[k];

    double I = t, m = A4;
    #pragma unroll
    for (int d = 1; d <= 32; d <<= 1) {
        double up = __shfl_up(I, d, 64);
        if (lane >= d) I = m * up + I;
        m = m * m;
    }
    double cin = __shfl_up(I, 1, 64);
    if (lane == 0) cin = 0.0;

    double e = cin;
    #pragma unroll
    for (int k = 0; k < 4; ++k) {
        carry[base + (size_t)(s0 + k) * NCH] = (float)e;  // E_{s-1}
        e = A * e + (double)pv[k];
    }
}

// ---------- K3: fused scan + elementwise ----------
// Restructured for ILP: (1) all x loads + carry load hoisted (one vmcnt wait);
// (2) the 4 within-block Kogge-Stone scans are carry-INDEPENDENT -> 24
// independent shuffle chains (4 it x 6 ch) instead of a serial
// scan->carry->scan chain; (3) carry fixup afterwards is 4 scalar fmas per
// channel, bitwise-identical to the old shfl(bias,63) chain since
// ap1(lane63)=A64 and S(63)=z.
__global__ __launch_bounds__(256) void k_apply(
    const float* __restrict__ imu,
    const float* __restrict__ eps0,
    const float* __restrict__ epw,
    const float* __restrict__ mn,
    const float* __restrict__ carry,
    float* __restrict__ out)
{
    int lane = threadIdx.x & 63;
    int w = blockIdx.x * 4 + (threadIdx.x >> 6);
    int b = w / NS, s = w % NS;

    float ap1, arev; lane_pows(lane, ap1, arev);
    const float A64 = a_pow64();
    int l0 = s * SPAN;

    // hoist all innovation loads + span carry (independent addresses)
    float x[NIT][6];
    #pragma unroll
    for (int it = 0; it < NIT; ++it)
        load_x(epw, eps0, b, l0 + it * 64 + lane, x[it]);

    float e[6];
    #pragma unroll
    for (int c = 0; c < 6; ++c) e[c] = carry[(size_t)w * NCH + c];

    // 24 independent Kogge-Stone chains, in place (S aliases x)
    float m = AF;
    #pragma unroll
    for (int d = 1; d < 64; d <<= 1) {
        #pragma unroll
        for (int it = 0; it < NIT; ++it) {
            #pragma unroll
            for (int c = 0; c < 6; ++c) {
                float up = __shfl_up(x[it][c], d, 64);
                if (lane >= d) x[it][c] = fmaf(m, up, x[it][c]);
            }
        }
        m *= m;
    }

    // carry fixup: bias(it) = ap1*e(it) + S(it); e(it+1) = A64*e(it) + S(it)@63
    #pragma unroll
    for (int c = 0; c < 6; ++c) {
        float ec = e[c];
        #pragma unroll
        for (int it = 0; it < NIT; ++it) {
            float z = __shfl(x[it][c], 63, 64);
            x[it][c] = fmaf(ap1, ec, x[it][c]);   // x now holds bias
            ec = fmaf(A64, ec, z);
        }
    }

    // elementwise apply (coalesced float2 IO), loads independent per it
    const float inv   = 1.0f / 65535.0f;
    const float twopi = 6.283185307179586f;
    #pragma unroll
    for (int it = 0; it < NIT; ++it) {
        int l = l0 + it * 64 + lane;
        float tt = (float)l * inv;
        float temp = fmaf(5.0f, __sinf(twopi * tt), fmaf(2.0f, tt, 20.0f));
        float ta = temp * 0.001f, tg = temp * 0.01f;

        size_t roff = (size_t)b * ROW + (size_t)l * NCH;
        const float2* ip = (const float2*)(imu + roff);
        const float2* mp = (const float2*)(mn + roff);
        float2* op = (float2*)(out + roff);
        float2 i0 = ip[0], i1 = ip[1], i2 = ip[2];
        float2 m0 = mp[0], m1 = mp[1], m2 = mp[2];
        float2 o0, o1, o2;
        o0.x = i0.x + x[it][0] + m0.x * 0.1f  + ta;
        o0.y = i0.y + x[it][1] + m0.y * 0.1f  + ta;
        o1.x = i1.x + x[it][2] + m1.x * 0.1f  + ta;
        o1.y = i1.y + x[it][3] + m1.y * 0.01f + tg;
        o2.x = i2.x + x[it][4] + m2.x * 0.01f + tg;
        o2.y = i2.y + x[it][5] + m2.y * 0.01f + tg;
        op[0] = o0; op[1] = o1; op[2] = o2;
    }
}

extern "C" void kernel_launch(void* const* d_in, const int* in_sizes, int n_in,
                              void* d_out, int out_size, void* d_ws, size_t ws_size,
                              hipStream_t stream) {
    const float* imu  = (const float*)d_in[0];   // [B, L, 6]
    const float* eps0 = (const float*)d_in[1];   // [B, 6]
    const float* epw  = (const float*)d_in[2];   // [B, L-1, 6]
    const float* mn   = (const float*)d_in[3];   // [B, L, 6]
    float* out = (float*)d_out;

    float* part  = (float*)d_ws;                 // NWAVE*6 floats
    float* carry = part + (size_t)NWAVE * NCH;   // NWAVE*6 floats

    k_partials<<<NWAVE / 4, 256, 0, stream>>>(eps0, epw, part);
    k_scan<<<Bn * NCH, 64, 0, stream>>>(part, carry);
    k_apply<<<NWAVE / 4, 256, 0, stream>>>(imu, eps0, epw, mn, carry, out);
}